// Round 1
// 236.800 us; speedup vs baseline: 1.0417x; 1.0417x over previous
//
#include <hip/hip_runtime.h>
#include <math.h>

// SpecNorm: x[B,T,F,2] fp32 -> x * rsqrt(ema(|x|) + eps)
// EMA sequential in T; alpha=0.9 => 128-step lookback reconstructs state to
// ~1e-6 (threshold 0.129).
//
// R5: R4 ran at MLP~=1 (VGPR_Count=32 proved the unroll-8 was register-
// minimized into a serial load->use->store loop; 1030 cyc/row ~= one memory
// round-trip). This version hand-pipelines: 8-row register batches, double-
// buffered (issue batch k+1's 8 loads BEFORE computing/storing batch k), so
// 8 KB/wave stays in flight and load-waits never drain store acks (loads are
// older than the following stores in the vmcnt queue). Also: single vf4
// nontemporal store per row (A+B halves adjacent) removes the every-other-8B
// partial-sector write pattern (WRITE_SIZE 138.5 -> ~124 MB). Chunks
// rebalanced to OUT0=200/OUTN=120 so warmup (128) and both output counts are
// multiples of 8 -- no serial remainder tails.

#define ALPHA 0.9f
#define OMA   0.1f
#define EPS_  1e-12f

// aligned(8): row base float-index is (b*2000+t)*962 == 2t mod 4, so odd
// rows give only 8 B alignment for the per-thread quad.
typedef float vf4 __attribute__((ext_vector_type(4), aligned(8)));
typedef float vf2 __attribute__((ext_vector_type(2), aligned(8)));

constexpr int B_ = 16, T_ = 2000, F_ = 481;
constexpr int NCH = 16, LOOKBACK = 128;
constexpr int OUT0 = 200, OUTN = 120;   // 200 + 15*120 = 2000; all %8 == 0
constexpr int ROWF = 2 * F_;            // 962 floats per row

// Load 8 consecutive rows into named registers (8 independent dwordx4 loads
// issued back-to-back => MLP 8), then advance the read pointer.
#define LD8(V) do { \
  V##0 = *(const vf4*)(xp + 0 * ROWF); \
  V##1 = *(const vf4*)(xp + 1 * ROWF); \
  V##2 = *(const vf4*)(xp + 2 * ROWF); \
  V##3 = *(const vf4*)(xp + 3 * ROWF); \
  V##4 = *(const vf4*)(xp + 4 * ROWF); \
  V##5 = *(const vf4*)(xp + 5 * ROWF); \
  V##6 = *(const vf4*)(xp + 6 * ROWF); \
  V##7 = *(const vf4*)(xp + 7 * ROWF); \
  xp += 8 * ROWF; \
} while (0)

#define EMA1(v) do { \
  float aA = __builtin_amdgcn_sqrtf((v).x * (v).x + (v).y * (v).y); \
  float aB = __builtin_amdgcn_sqrtf((v).z * (v).z + (v).w * (v).w); \
  sA = ALPHA * sA + OMA * aA; \
  sB = ALPHA * sB + OMA * aB; \
} while (0)

#define EMA8(V) do { EMA1(V##0); EMA1(V##1); EMA1(V##2); EMA1(V##3); \
                     EMA1(V##4); EMA1(V##5); EMA1(V##6); EMA1(V##7); } while (0)

// One output row: EMA update, rsqrt, single contiguous 16 B nt store per lane
// (tid==240 stores only its valid 8 B A-half; a 16 B store there would
// clobber the next row's f=0, owned by tid 0 of this block).
#define OUT1(v) do { \
  EMA1(v); \
  float iA = __builtin_amdgcn_rsqf(sA + EPS_); \
  float iB = __builtin_amdgcn_rsqf(sB + EPS_); \
  if (hasB) { \
    vf4 o = { (v).x * iA, (v).y * iA, (v).z * iB, (v).w * iB }; \
    __builtin_nontemporal_store(o, (vf4*)op); \
  } else { \
    vf2 o = { (v).x * iA, (v).y * iA }; \
    __builtin_nontemporal_store(o, (vf2*)op); \
  } \
  op += ROWF; \
} while (0)

#define OUT8(V) do { OUT1(V##0); OUT1(V##1); OUT1(V##2); OUT1(V##3); \
                     OUT1(V##4); OUT1(V##5); OUT1(V##6); OUT1(V##7); } while (0)

#define CP8() do { a0 = b0; a1 = b1; a2 = b2; a3 = b3; \
                   a4 = b4; a5 = b5; a6 = b6; a7 = b7; } while (0)

__global__ __launch_bounds__(256, 1)
void specnorm_kernel(const float* __restrict__ x, float* __restrict__ out,
                     float* __restrict__ ws) {
    const int tid = threadIdx.x;
    if (tid > 240) return;              // 241..255 idle (6% waste)
    const int chunk = blockIdx.x;
    const int b = blockIdx.y;
    const bool hasB = (tid < 240);      // tid==240 owns only f=480

    // s0[f] = 0.001 + f*step
    const float step = (float)((0.0001 - 0.001) / (double)(F_ - 1));
    float sA = 0.001f + (float)(2 * tid) * step;
    float sB = 0.001f + (float)(2 * tid + 1) * step;

    const int tout0 = (chunk == 0) ? 0 : OUT0 + (chunk - 1) * OUTN;
    const int nout  = (chunk == 0) ? OUT0 : OUTN;
    const int nwarm = (chunk == 0) ? 0 : LOOKBACK;
    const int tstart = tout0 - nwarm;

    // NOTE: tid==240's 16 B load reads 8 B past the row (= next row's f=0,
    // harmless). At the very last row of the buffer this over-reads 8 B past
    // the end; allocation is page-granular with ~2 KB slack (123,136,000 B
    // is not page-multiple), so the access stays mapped.
    const float* xp = x + (size_t)(b * T_ + tstart) * ROWF + 4 * tid;
    float* op = out + (size_t)(b * T_ + tout0) * ROWF + 4 * tid;
    (void)ws;

    vf4 a0, a1, a2, a3, a4, a5, a6, a7;
    vf4 b0, b1, b2, b3, b4, b5, b6, b7;

    // ---- warmup: EMA only, no stores (chunk 0 skips; 128 = 16 batches) ----
    if (nwarm > 0) {
        LD8(a);
        for (int t = 8; t < LOOKBACK; t += 8) {
            LD8(b);          // next batch's loads in flight during EMA
            EMA8(a);
            CP8();
        }
        EMA8(a);
    }

    // ---- main: EMA + normalize + store (nout % 8 == 0) ----
    LD8(a);
    for (int t = 8; t < nout; t += 8) {
        LD8(b);              // loads issued BEFORE this batch's stores
        OUT8(a);
        CP8();
    }
    OUT8(a);
}

extern "C" void kernel_launch(void* const* d_in, const int* in_sizes, int n_in,
                              void* d_out, int out_size, void* d_ws, size_t ws_size,
                              hipStream_t stream) {
    const float* x = (const float*)d_in[0];
    float* out = (float*)d_out;
    float* ws = (float*)d_ws;

    dim3 grid(NCH, B_);          // 256 blocks x 4 waves = 1024 waves
    dim3 block(256);
    specnorm_kernel<<<grid, block, 0, stream>>>(x, out, ws);
}